// Round 7
// baseline (213.560 us; speedup 1.0000x reference)
//
#include <hip/hip_runtime.h>
#include <cstdint>

#define DIN 2048
#define ROWS 9
#define SCALE_F 0.35355339059327373f
#define EPS_F 1e-6f

// 512 threads/block, 512 blocks, grid-stride (16 positions/block). Thread t
// owns elements [4t,4t+4) of every row; weight slices (32+32 floats) live in
// VGPRs for the whole kernel. Software-pipelined ACROSS the barrier: position
// p+stride's 9 row-loads are issued as position p's values are extracted
// (register-neutral: same v[] regs), and the barrier is a raw s_barrier with
// lgkmcnt(0) only -- NO vmcnt drain -- so the HBM queue never empties.
// LDS partials are parity-double-buffered; per-row sumsq reduced inline
// (frees the ssv[9] array -> fits 128 VGPR without spills).
__global__ __launch_bounds__(512, 4)
void router_kernel(const float* __restrict__ x, const float* __restrict__ bax,
                   const float* __restrict__ Wq, const float* __restrict__ bq,
                   const float* __restrict__ Wk, const float* __restrict__ bk,
                   float* __restrict__ out, int positions) {
    __shared__ float red[2][ROWS][8][13];  // [parity][row][wave][chan 0..7, ss at 8, pad]

    const int t = threadIdx.x;    // 0..511
    const int w = t >> 6;         // wave 0..7
    const int lane = t & 63;
    const int kn = lane >> 3;     // key index (wave-0 tail)
    const int hh = lane & 7;      // hidden col (wave-0 tail)
    const int chan = ((lane & 1) << 2) | (lane & 2) | ((lane & 4) >> 2);
    const int widx = (lane < 8) ? chan : 8;

    // ---- weight slices: rows [4t,4t+4) x 8 cols = 32 floats each, in VGPRs ----
    float wq[32], wk[32];
    {
        const float4* q4 = (const float4*)(Wq + 32 * t);
        const float4* k4 = (const float4*)(Wk + 32 * t);
#pragma unroll
        for (int j = 0; j < 8; ++j) {
            float4 a = q4[j];
            wq[4 * j + 0] = a.x; wq[4 * j + 1] = a.y;
            wq[4 * j + 2] = a.z; wq[4 * j + 3] = a.w;
        }
#pragma unroll
        for (int j = 0; j < 8; ++j) {
            float4 b = k4[j];
            wk[4 * j + 0] = b.x; wk[4 * j + 1] = b.y;
            wk[4 * j + 2] = b.z; wk[4 * j + 3] = b.w;
        }
    }
    const float bkh = bk[hh];
    const float bqh = bq[hh];

    const int stride = gridDim.x;
    long p = blockIdx.x;
    if (p >= positions) return;

    // ---- prologue: first position's 9 row loads ----
    float4 v[ROWS];
    {
        const float4* xr = (const float4*)(x + p * (long)DIN) + t;
        const float4* br = (const float4*)(bax + p * (long)(8 * DIN)) + t;
        v[0] = xr[0];
#pragma unroll
        for (int r = 1; r < ROWS; ++r) v[r] = br[(r - 1) * (DIN / 4)];
    }

    int buf = 0;
    for (; p < positions; p += stride, buf ^= 1) {
        const long pn = (p + stride < positions) ? (p + stride) : p;  // clamp: L2 re-read
        const float4* xr_n = (const float4*)(x + pn * (long)DIN) + t;
        const float4* br_n = (const float4*)(bax + pn * (long)(8 * DIN)) + t;

#pragma unroll
        for (int r = 0; r < ROWS; ++r) {
            const float e0 = v[r].x, e1 = v[r].y, e2 = v[r].z, e3 = v[r].w;
            // issue next position's row r into the just-freed registers
            if (r == 0) v[0] = xr_n[0];
            else        v[r] = br_n[(r - 1) * (DIN / 4)];

            // sumsq partial
            float ss = fmaf(e3, e3, fmaf(e2, e2, fmaf(e1, e1, e0 * e0)));

            // dot partials for all 8 hidden cols over this thread's 4 elements
            const float* wa = (r == 0) ? wq : wk;   // r is unroll-constant
            float pd[8];
#pragma unroll
            for (int h = 0; h < 8; ++h)
                pd[h] = fmaf(e3, wa[24 + h],
                         fmaf(e2, wa[16 + h],
                          fmaf(e1, wa[8 + h], e0 * wa[h])));

            // in-group-of-8 transpose reduce: 8 channels -> 1 per lane
            float r1[4];
#pragma unroll
            for (int i = 0; i < 4; ++i) {
                float keep = (lane & 1) ? pd[i + 4] : pd[i];
                float send = (lane & 1) ? pd[i] : pd[i + 4];
                r1[i] = keep + __shfl_xor(send, 1);
            }
            float r2[2];
#pragma unroll
            for (int i = 0; i < 2; ++i) {
                float keep = (lane & 2) ? r1[i + 2] : r1[i];
                float send = (lane & 2) ? r1[i] : r1[i + 2];
                r2[i] = keep + __shfl_xor(send, 2);
            }
            float keep = (lane & 4) ? r2[1] : r2[0];
            float send = (lane & 4) ? r2[0] : r2[1];
            float dv = keep + __shfl_xor(send, 4);
            // cross-group (8 groups per wave)
            dv += __shfl_xor(dv, 8);
            dv += __shfl_xor(dv, 16);
            dv += __shfl_xor(dv, 32);

            // sumsq: full 64-lane butterfly (inline; no persistent array)
            ss += __shfl_xor(ss, 1);
            ss += __shfl_xor(ss, 2);
            ss += __shfl_xor(ss, 4);
            ss += __shfl_xor(ss, 8);
            ss += __shfl_xor(ss, 16);
            ss += __shfl_xor(ss, 32);

            if (lane < 9) red[buf][r][w][widx] = (lane < 8) ? dv : ss;
        }

        // raw barrier: drain LDS writes only -- global prefetches stay in flight
        asm volatile("s_waitcnt lgkmcnt(0)" ::: "memory");
        asm volatile("s_barrier" ::: "memory");

        // ---- wave 0: normalize + scores + softmax + store ----
        if (w == 0) {
            float dtk = 0.f, ssk = 0.f, dtq = 0.f, ssq = 0.f;
#pragma unroll
            for (int wv = 0; wv < 8; ++wv) {
                dtk += red[buf][kn + 1][wv][hh];
                ssk += red[buf][kn + 1][wv][8];
                dtq += red[buf][0][wv][hh];
                ssq += red[buf][0][wv][8];
            }
            float kval = fmaf(dtk, rsqrtf(ssk + EPS_F), bkh);
            float qval = fmaf(dtq, rsqrtf(ssq + EPS_F), bqh);
            // score_kn = SCALE * sum_h q[h]*k[kn][h]
            float s = qval * kval;
            s += __shfl_xor(s, 1);
            s += __shfl_xor(s, 2);
            s += __shfl_xor(s, 4);
            s *= SCALE_F;
            // softmax across the 8 key-groups
            float mx = s;
            mx = fmaxf(mx, __shfl_xor(mx, 8));
            mx = fmaxf(mx, __shfl_xor(mx, 16));
            mx = fmaxf(mx, __shfl_xor(mx, 32));
            float ev = __expf(s - mx);
            float den = ev;
            den += __shfl_xor(den, 8);
            den += __shfl_xor(den, 16);
            den += __shfl_xor(den, 32);
            if (hh == 0) out[p * 8 + kn] = ev / den;
        }
    }
}

extern "C" void kernel_launch(void* const* d_in, const int* in_sizes, int n_in,
                              void* d_out, int out_size, void* d_ws, size_t ws_size,
                              hipStream_t stream) {
    const float* x   = (const float*)d_in[0];
    const float* bax = (const float*)d_in[1];
    const float* Wq  = (const float*)d_in[2];
    const float* bq  = (const float*)d_in[3];
    const float* Wk  = (const float*)d_in[4];
    const float* bk  = (const float*)d_in[5];
    float* out = (float*)d_out;

    const int positions = in_sizes[0] / DIN;   // B*S
    int nb = positions < 512 ? positions : 512;
    router_kernel<<<nb, 512, 0, stream>>>(x, bax, Wq, bq, Wk, bk, out, positions);
}

// Round 8
// 120.355 us; speedup vs baseline: 1.7744x; 1.7744x over previous
//
#include <hip/hip_runtime.h>
#include <cstdint>

#define SCALE_F 0.35355339059327373f
#define EPS_F 1e-6f

// raw barrier: drain LDS ops only -- global prefetch loads stay in flight
#define BARRIER() do { \
    asm volatile("s_waitcnt lgkmcnt(0)" ::: "memory"); \
    __builtin_amdgcn_s_barrier(); \
    asm volatile("" ::: "memory"); \
} while (0)

// per-row: extract, prefetch into just-freed regs, sumsq, 8-col dot partials,
// in-octet transpose reduce + cross-group butterfly, stash wave partial
#define ROW_BODY(R, BUF, PREFETCH) do { \
    const float e0 = v[R].x, e1 = v[R].y, e2 = v[R].z, e3 = v[R].w; \
    PREFETCH; \
    ssv[R] = fmaf(e3, e3, fmaf(e2, e2, fmaf(e1, e1, e0 * e0))); \
    float pd[8]; \
    _Pragma("unroll") \
    for (int h = 0; h < 8; ++h) \
        pd[h] = fmaf(e3, wreg[24 + h], fmaf(e2, wreg[16 + h], \
                 fmaf(e1, wreg[8 + h], e0 * wreg[h]))); \
    float r1[4]; \
    _Pragma("unroll") \
    for (int i = 0; i < 4; ++i) { \
        float keep = (lane & 1) ? pd[i + 4] : pd[i]; \
        float send = (lane & 1) ? pd[i] : pd[i + 4]; \
        r1[i] = keep + __shfl_xor(send, 1); \
    } \
    float r2[2]; \
    _Pragma("unroll") \
    for (int i = 0; i < 2; ++i) { \
        float keep = (lane & 2) ? r1[i + 2] : r1[i]; \
        float send = (lane & 2) ? r1[i] : r1[i + 2]; \
        r2[i] = keep + __shfl_xor(send, 2); \
    } \
    { \
        float keep = (lane & 4) ? r2[1] : r2[0]; \
        float send = (lane & 4) ? r2[0] : r2[1]; \
        float dv = keep + __shfl_xor(send, 4); \
        dv += __shfl_xor(dv, 8); \
        dv += __shfl_xor(dv, 16); \
        dv += __shfl_xor(dv, 32); \
        if (lane < 8) red[BUF][R][w][chan] = dv; \
    } \
} while (0)

// one transpose-reduce collapses all 8 rows' sumsq partials
#define SS_REDUCE(BUF) do { \
    float r1[4]; \
    _Pragma("unroll") \
    for (int i = 0; i < 4; ++i) { \
        float keep = (lane & 1) ? ssv[i + 4] : ssv[i]; \
        float send = (lane & 1) ? ssv[i] : ssv[i + 4]; \
        r1[i] = keep + __shfl_xor(send, 1); \
    } \
    float r2[2]; \
    _Pragma("unroll") \
    for (int i = 0; i < 2; ++i) { \
        float keep = (lane & 2) ? r1[i + 2] : r1[i]; \
        float send = (lane & 2) ? r1[i] : r1[i + 2]; \
        r2[i] = keep + __shfl_xor(send, 2); \
    } \
    float keep = (lane & 4) ? r2[1] : r2[0]; \
    float send = (lane & 4) ? r2[0] : r2[1]; \
    float sv = keep + __shfl_xor(send, 4); \
    sv += __shfl_xor(sv, 8); \
    sv += __shfl_xor(sv, 16); \
    sv += __shfl_xor(sv, 32); \
    if (lane < 8) red[BUF][chan][w][8] = sv; \
} while (0)

// 512 threads/block, 16 positions/block (grid = positions/16). Thread t owns
// elements [4t,4t+4). Phase 1: the block's 16 x-rows (2 batches of 8) with
// Wq slice in regs -> q vectors into LDS. Then wreg is RELOADED with Wk
// (zero overlap: only 32 weight regs ever live) and phase 2 streams 16x8 key
// rows with cross-barrier prefetch + raw s_barrier (no vmcnt drain) -- the
// HBM queue never empties. ~110 VGPR: fits (512,4) = 2 blocks/CU, no spill.
__global__ __launch_bounds__(512, 4)
void router_kernel(const float* __restrict__ x, const float* __restrict__ bax,
                   const float* __restrict__ Wq, const float* __restrict__ bq,
                   const float* __restrict__ Wk, const float* __restrict__ bk,
                   float* __restrict__ out, int positions) {
    __shared__ float red[2][8][8][13];  // [parity][row][wave][chan 0..7, ss at 8, pad]
    __shared__ float qls[16][8];        // per-position query vectors

    const int t = threadIdx.x;    // 0..511
    const int w = t >> 6;         // wave 0..7
    const int lane = t & 63;
    const int chan = ((lane & 1) << 2) | (lane & 2) | ((lane & 4) >> 2);
    const long pmax = positions - 1;
    const long pb = (long)blockIdx.x * 16;

    const float4* x4 = (const float4*)x + t;     // + p*512 per row
    const float4* b4 = (const float4*)bax + t;   // + (p*8+r)*512 per row

    // ---- weight slice (phase 1: Wq) ----
    float wreg[32];
    {
        const float4* q4 = (const float4*)(Wq + 32 * t);
#pragma unroll
        for (int j = 0; j < 8; ++j) {
            float4 a = q4[j];
            wreg[4 * j + 0] = a.x; wreg[4 * j + 1] = a.y;
            wreg[4 * j + 2] = a.z; wreg[4 * j + 3] = a.w;
        }
    }
    const float bqh = bq[lane & 7];
    const float bkh = bk[lane & 7];

    float4 v[8];
    float ssv[8];

    // prologue: phase-1 batch 0 (x rows of positions pb..pb+7)
#pragma unroll
    for (int r = 0; r < 8; ++r) {
        long p = pb + r; if (p > pmax) p = pmax;
        v[r] = x4[p * 512];
    }

    // ---------- PHASE 1, batch 0 ----------
#pragma unroll
    for (int r = 0; r < 8; ++r) {
        long p = pb + 8 + r; if (p > pmax) p = pmax;
        ROW_BODY(r, 0, v[r] = x4[p * 512]);
    }
    SS_REDUCE(0);
    BARRIER();
    if (w == 0) {   // q vectors for positions pb..pb+7
        const int pr = lane >> 3, h = lane & 7;
        float dt = 0.f, ss = 0.f;
#pragma unroll
        for (int wv = 0; wv < 8; ++wv) {
            dt += red[0][pr][wv][h];
            ss += red[0][pr][wv][8];
        }
        qls[pr][h] = fmaf(dt, rsqrtf(ss + EPS_F), bqh);
    }

    // ---------- PHASE 1, batch 1 (prefetch = phase-2 iter 0 key rows) ----------
    {
        long p0 = pb; if (p0 > pmax) p0 = pmax;
#pragma unroll
        for (int r = 0; r < 8; ++r) {
            ROW_BODY(r, 1, v[r] = b4[(p0 * 8 + r) * 512]);
        }
    }
    SS_REDUCE(1);
    // reload wreg <- Wk slice (wq dead; no peak-pressure overlap)
    {
        const float4* k4 = (const float4*)(Wk + 32 * t);
#pragma unroll
        for (int j = 0; j < 8; ++j) {
            float4 a = k4[j];
            wreg[4 * j + 0] = a.x; wreg[4 * j + 1] = a.y;
            wreg[4 * j + 2] = a.z; wreg[4 * j + 3] = a.w;
        }
    }
    BARRIER();
    if (w == 0) {   // q vectors for positions pb+8..pb+15
        const int pr = lane >> 3, h = lane & 7;
        float dt = 0.f, ss = 0.f;
#pragma unroll
        for (int wv = 0; wv < 8; ++wv) {
            dt += red[1][pr][wv][h];
            ss += red[1][pr][wv][8];
        }
        qls[8 + pr][h] = fmaf(dt, rsqrtf(ss + EPS_F), bqh);
    }

    // ---------- PHASE 2: 16 positions x 8 key rows ----------
#pragma unroll 1
    for (int j = 0; j < 16; ++j) {
        const int bf = j & 1;
        long p = pb + j; if (p > pmax) p = pmax;
        long pn = pb + j + 1; if (pn > pmax) pn = pmax;
        const bool pref = (j < 15);
#pragma unroll
        for (int r = 0; r < 8; ++r) {
            ROW_BODY(r, bf, if (pref) v[r] = b4[(pn * 8 + r) * 512]);
        }
        SS_REDUCE(bf);
        BARRIER();
        if (w == 0) {
            const int kn = lane >> 3, hh = lane & 7;
            float dtk = 0.f, ssk = 0.f;
#pragma unroll
            for (int wv = 0; wv < 8; ++wv) {
                dtk += red[bf][kn][wv][hh];
                ssk += red[bf][kn][wv][8];
            }
            float kval = fmaf(dtk, rsqrtf(ssk + EPS_F), bkh);
            float qv = qls[j][hh];
            // score for key kn: reduce q[h]*k[kn][h] within the octet
            float s = qv * kval;
            s += __shfl_xor(s, 1);
            s += __shfl_xor(s, 2);
            s += __shfl_xor(s, 4);
            s *= SCALE_F;
            // softmax across the 8 key octets
            float mx = s;
            mx = fmaxf(mx, __shfl_xor(mx, 8));
            mx = fmaxf(mx, __shfl_xor(mx, 16));
            mx = fmaxf(mx, __shfl_xor(mx, 32));
            float ev = __expf(s - mx);
            float den = ev;
            den += __shfl_xor(den, 8);
            den += __shfl_xor(den, 16);
            den += __shfl_xor(den, 32);
            if (hh == 0 && pb + j < positions) out[p * 8 + kn] = ev / den;
        }
    }
}

extern "C" void kernel_launch(void* const* d_in, const int* in_sizes, int n_in,
                              void* d_out, int out_size, void* d_ws, size_t ws_size,
                              hipStream_t stream) {
    const float* x   = (const float*)d_in[0];
    const float* bax = (const float*)d_in[1];
    const float* Wq  = (const float*)d_in[2];
    const float* bq  = (const float*)d_in[3];
    const float* Wk  = (const float*)d_in[4];
    const float* bk  = (const float*)d_in[5];
    float* out = (float*)d_out;

    const int positions = in_sizes[0] / 2048;   // B*S
    const int nb = (positions + 15) / 16;
    router_kernel<<<nb, 512, 0, stream>>>(x, bax, Wq, bq, Wk, bk, out, positions);
}

// Round 9
// 114.420 us; speedup vs baseline: 1.8664x; 1.0519x over previous
//
#include <hip/hip_runtime.h>
#include <cstdint>

#define SCALE_F 0.35355339059327373f
#define EPS_F 1e-6f

// ---- VALU cross-lane primitives (DPP / permlane), replacing DS-pipe shuffles ----
template <int CTRL>
__device__ __forceinline__ float dppf(float s) {   // fetch via DPP pattern CTRL
    return __int_as_float(__builtin_amdgcn_update_dpp(
        0, __float_as_int(s), CTRL, 0xF, 0xF, true));
}
template <int PAT>
__device__ __forceinline__ float swz(float s) {    // ds_swizzle fetch (DS pipe)
    return __int_as_float(__builtin_amdgcn_ds_swizzle(__float_as_int(s), PAT));
}
// x[l] + x[l^32] via permlane32_swap: {r0,r1} = {x.lo,x.hi} in some order -> sum is
// selection-convention-independent. Same trick for max.
__device__ __forceinline__ float bf32s(float x) {
    auto r = __builtin_amdgcn_permlane32_swap(__float_as_int(x), __float_as_int(x),
                                              false, false);
    return __int_as_float(r[0]) + __int_as_float(r[1]);
}
__device__ __forceinline__ float bf32m(float x) {
    auto r = __builtin_amdgcn_permlane32_swap(__float_as_int(x), __float_as_int(x),
                                              false, false);
    return fmaxf(__int_as_float(r[0]), __int_as_float(r[1]));
}
#define DPP_X1 0xB1    // quad_perm [1,0,3,2] : exact l^1
#define DPP_X2 0x4E    // quad_perm [2,3,0,1] : exact l^2
#define DPP_R8 0x128   // row_ror:8          : exact l^8 (within 16-lane row)
#define DPP_HM 0x141   // row_half_mirror    : cross-quad pair within octet
#define SWZ_X4  0x101F // ds_swizzle xor 4
#define SWZ_X16 0x401F // ds_swizzle xor 16

// raw barrier: drain LDS ops only -- global prefetch loads stay in flight
#define BARRIER() do { \
    asm volatile("s_waitcnt lgkmcnt(0)" ::: "memory"); \
    __builtin_amdgcn_s_barrier(); \
    asm volatile("" ::: "memory"); \
} while (0)

// per-row: extract, prefetch into just-freed regs, sumsq, 8-col dot partials,
// transpose-reduce (DPP stages + 1 ds_swizzle) + all-VALU-dominant butterfly
#define ROW_BODY(R, BUF, PREFETCH) do { \
    const float e0 = v[R].x, e1 = v[R].y, e2 = v[R].z, e3 = v[R].w; \
    PREFETCH; \
    ssv[R] = fmaf(e3, e3, fmaf(e2, e2, fmaf(e1, e1, e0 * e0))); \
    float pd[8]; \
    _Pragma("unroll") \
    for (int h = 0; h < 8; ++h) \
        pd[h] = fmaf(e3, wreg[24 + h], fmaf(e2, wreg[16 + h], \
                 fmaf(e1, wreg[8 + h], e0 * wreg[h]))); \
    float r1[4]; \
    _Pragma("unroll") \
    for (int i = 0; i < 4; ++i) { \
        float keep = (lane & 1) ? pd[i + 4] : pd[i]; \
        float send = (lane & 1) ? pd[i] : pd[i + 4]; \
        r1[i] = keep + dppf<DPP_X1>(send); \
    } \
    float r2[2]; \
    _Pragma("unroll") \
    for (int i = 0; i < 2; ++i) { \
        float keep = (lane & 2) ? r1[i + 2] : r1[i]; \
        float send = (lane & 2) ? r1[i] : r1[i + 2]; \
        r2[i] = keep + dppf<DPP_X2>(send); \
    } \
    { \
        float keep = (lane & 4) ? r2[1] : r2[0]; \
        float send = (lane & 4) ? r2[0] : r2[1]; \
        float dv = keep + swz<SWZ_X4>(send); \
        dv += dppf<DPP_R8>(dv); \
        dv += swz<SWZ_X16>(dv); \
        dv = bf32s(dv); \
        if (lane < 8) red[BUF][R][w][chan] = dv; \
    } \
} while (0)

// one transpose-reduce collapses all 8 rows' sumsq partials
#define SS_REDUCE(BUF) do { \
    float r1[4]; \
    _Pragma("unroll") \
    for (int i = 0; i < 4; ++i) { \
        float keep = (lane & 1) ? ssv[i + 4] : ssv[i]; \
        float send = (lane & 1) ? ssv[i] : ssv[i + 4]; \
        r1[i] = keep + dppf<DPP_X1>(send); \
    } \
    float r2[2]; \
    _Pragma("unroll") \
    for (int i = 0; i < 2; ++i) { \
        float keep = (lane & 2) ? r1[i + 2] : r1[i]; \
        float send = (lane & 2) ? r1[i] : r1[i + 2]; \
        r2[i] = keep + dppf<DPP_X2>(send); \
    } \
    float keep = (lane & 4) ? r2[1] : r2[0]; \
    float send = (lane & 4) ? r2[0] : r2[1]; \
    float sv = keep + swz<SWZ_X4>(send); \
    sv += dppf<DPP_R8>(sv); \
    sv += swz<SWZ_X16>(sv); \
    sv = bf32s(sv); \
    if (lane < 8) red[BUF][chan][w][8] = sv; \
} while (0)

// 512 threads/block, 16 positions/block. Thread t owns elements [4t,4t+4).
// Phase 1: 16 x-rows (2 batches of 8) with Wq slice in regs -> q vectors in
// LDS; wreg reloaded with Wk; phase 2 streams 16x8 key rows with
// cross-barrier prefetch + raw s_barrier (no vmcnt drain). Reductions are
// DPP/permlane (VALU pipe); DS-pipe ops per row-wave ~3.5 vs ~11 before.
__global__ __launch_bounds__(512, 4)
void router_kernel(const float* __restrict__ x, const float* __restrict__ bax,
                   const float* __restrict__ Wq, const float* __restrict__ bq,
                   const float* __restrict__ Wk, const float* __restrict__ bk,
                   float* __restrict__ out, int positions) {
    __shared__ float red[2][8][8][13];  // [parity][row][wave][chan 0..7, ss at 8, pad]
    __shared__ float qls[16][8];        // per-position query vectors

    const int t = threadIdx.x;    // 0..511
    const int w = t >> 6;         // wave 0..7
    const int lane = t & 63;
    const int chan = ((lane & 1) << 2) | (lane & 2) | ((lane & 4) >> 2);
    const long pmax = positions - 1;
    const long pb = (long)blockIdx.x * 16;

    const float4* x4 = (const float4*)x + t;     // + p*512 per row
    const float4* b4 = (const float4*)bax + t;   // + (p*8+r)*512 per row

    // ---- weight slice (phase 1: Wq) ----
    float wreg[32];
    {
        const float4* q4 = (const float4*)(Wq + 32 * t);
#pragma unroll
        for (int j = 0; j < 8; ++j) {
            float4 a = q4[j];
            wreg[4 * j + 0] = a.x; wreg[4 * j + 1] = a.y;
            wreg[4 * j + 2] = a.z; wreg[4 * j + 3] = a.w;
        }
    }
    const float bqh = bq[lane & 7];
    const float bkh = bk[lane & 7];

    float4 v[8];
    float ssv[8];

    // prologue: phase-1 batch 0 (x rows of positions pb..pb+7)
#pragma unroll
    for (int r = 0; r < 8; ++r) {
        long p = pb + r; if (p > pmax) p = pmax;
        v[r] = x4[p * 512];
    }

    // ---------- PHASE 1, batch 0 ----------
#pragma unroll
    for (int r = 0; r < 8; ++r) {
        long p = pb + 8 + r; if (p > pmax) p = pmax;
        ROW_BODY(r, 0, v[r] = x4[p * 512]);
    }
    SS_REDUCE(0);
    BARRIER();
    if (w == 0) {   // q vectors for positions pb..pb+7
        const int pr = lane >> 3, h = lane & 7;
        float dt = 0.f, ss = 0.f;
#pragma unroll
        for (int wv = 0; wv < 8; ++wv) {
            dt += red[0][pr][wv][h];
            ss += red[0][pr][wv][8];
        }
        qls[pr][h] = fmaf(dt, rsqrtf(ss + EPS_F), bqh);
    }

    // ---------- PHASE 1, batch 1 (prefetch = phase-2 iter 0 key rows) ----------
    {
        long p0 = pb; if (p0 > pmax) p0 = pmax;
#pragma unroll
        for (int r = 0; r < 8; ++r) {
            ROW_BODY(r, 1, v[r] = b4[(p0 * 8 + r) * 512]);
        }
    }
    SS_REDUCE(1);
    // reload wreg <- Wk slice (wq dead; no peak-pressure overlap)
    {
        const float4* k4 = (const float4*)(Wk + 32 * t);
#pragma unroll
        for (int j = 0; j < 8; ++j) {
            float4 a = k4[j];
            wreg[4 * j + 0] = a.x; wreg[4 * j + 1] = a.y;
            wreg[4 * j + 2] = a.z; wreg[4 * j + 3] = a.w;
        }
    }
    BARRIER();
    if (w == 0) {   // q vectors for positions pb+8..pb+15
        const int pr = lane >> 3, h = lane & 7;
        float dt = 0.f, ss = 0.f;
#pragma unroll
        for (int wv = 0; wv < 8; ++wv) {
            dt += red[1][pr][wv][h];
            ss += red[1][pr][wv][8];
        }
        qls[8 + pr][h] = fmaf(dt, rsqrtf(ss + EPS_F), bqh);
    }

    // ---------- PHASE 2: 16 positions x 8 key rows ----------
#pragma unroll 1
    for (int j = 0; j < 16; ++j) {
        const int bf = j & 1;
        long p = pb + j; if (p > pmax) p = pmax;
        long pn = pb + j + 1; if (pn > pmax) pn = pmax;
        const bool pref = (j < 15);
#pragma unroll
        for (int r = 0; r < 8; ++r) {
            ROW_BODY(r, bf, if (pref) v[r] = b4[(pn * 8 + r) * 512]);
        }
        SS_REDUCE(bf);
        BARRIER();
        if (w == 0) {
            const int kn = lane >> 3, hh = lane & 7;
            float dtk = 0.f, ssk = 0.f;
#pragma unroll
            for (int wv = 0; wv < 8; ++wv) {
                dtk += red[bf][kn][wv][hh];
                ssk += red[bf][kn][wv][8];
            }
            float kval = fmaf(dtk, rsqrtf(ssk + EPS_F), bkh);
            float qv = qls[j][hh];
            // score for key kn: sum q[h]*k[kn][h] within the octet (all VALU)
            float s = qv * kval;
            s += dppf<DPP_X1>(s);
            s += dppf<DPP_X2>(s);
            s += dppf<DPP_HM>(s);   // quads uniform -> half_mirror completes octet
            s *= SCALE_F;
            // softmax across the 8 key octets (lanes l, l^8, l^16, l^32)
            float mx = fmaxf(s, dppf<DPP_R8>(s));
            mx = fmaxf(mx, swz<SWZ_X16>(mx));
            mx = bf32m(mx);
            float ev = __expf(s - mx);
            float den = ev + dppf<DPP_R8>(ev);
            den += swz<SWZ_X16>(den);
            den = bf32s(den);
            if (hh == 0 && pb + j < positions) out[p * 8 + kn] = ev / den;
        }
    }
}

extern "C" void kernel_launch(void* const* d_in, const int* in_sizes, int n_in,
                              void* d_out, int out_size, void* d_ws, size_t ws_size,
                              hipStream_t stream) {
    const float* x   = (const float*)d_in[0];
    const float* bax = (const float*)d_in[1];
    const float* Wq  = (const float*)d_in[2];
    const float* bq  = (const float*)d_in[3];
    const float* Wk  = (const float*)d_in[4];
    const float* bk  = (const float*)d_in[5];
    float* out = (float*)d_out;

    const int positions = in_sizes[0] / 2048;   // B*S
    const int nb = (positions + 15) / 16;
    router_kernel<<<nb, 512, 0, stream>>>(x, bax, Wq, bq, Wk, bk, out, positions);
}